// Round 6
// baseline (587.773 us; speedup 1.0000x reference)
//
#include <hip/hip_runtime.h>

#define NN 20000
#define EE 320000
#define BB 64
#define DD 256
#define DEPTH 3
#define NT (NN + BB)   // h rows + hs rows appended (NT = 20064 = 32*627 = 8*2508)

typedef __attribute__((ext_vector_type(8))) short short8;
typedef __attribute__((ext_vector_type(4))) float floatx4;

// ---------------------------------------------------------------- bf16 split helpers
__device__ __forceinline__ short f2bf(float x) {
  union { float f; unsigned u; } v; v.f = x;
  unsigned r = v.u + 0x7fffu + ((v.u >> 16) & 1u);  // RNE
  return (short)(r >> 16);
}
__device__ __forceinline__ float bf2f(short s) {
  union { unsigned u; float f; } v; v.u = ((unsigned)(unsigned short)s) << 16;
  return v.f;
}

// ---------------------------------------------------------------- reductions
__device__ __forceinline__ float blockSum256(float v, float* tmp) {
  #pragma unroll
  for (int o = 32; o > 0; o >>= 1) v += __shfl_down(v, o, 64);
  if ((threadIdx.x & 63) == 0) tmp[threadIdx.x >> 6] = v;
  __syncthreads();
  float r = tmp[0] + tmp[1] + tmp[2] + tmp[3];
  __syncthreads();
  return r;
}

// ---------------------------------------------------------------- M2/M3 -> split transposed B
// M2 = W2 @ linW[0:256,:], M3 = W3 @ linW[256:512,:]
// B'[k][n]: rows 0..255 = M2, 256..511 = M3. Stored as Bt_hi/lo[n][k] bf16 [256][512].
__global__ __launch_bounds__(256) void kM(const float* __restrict__ W2,
                                          const float* __restrict__ W3,
                                          const float* __restrict__ linW,
                                          short* __restrict__ Bth,
                                          short* __restrict__ Btl) {
  int i = blockIdx.x & 255;
  bool second = blockIdx.x >= 256;
  const float* W = second ? W3 : W2;
  const float* L = linW + (second ? DD * DD : 0);
  int j = threadIdx.x;
  float acc = 0.f;
  #pragma unroll 4
  for (int k = 0; k < DD; k++) acc = fmaf(W[i * DD + k], L[k * DD + j], acc);
  short hi = f2bf(acc);
  short lo = f2bf(acc - bf2f(hi));
  int kk = second ? (DD + i) : i;
  Bth[(size_t)j * 512 + kk] = hi;
  Btl[(size_t)j * 512 + kk] = lo;
}

// ---------------------------------------------------------------- count (first) + encode (wave-per-row)
#define NCB ((EE + 255) / 256)   // 1250 count blocks, scheduled first
__global__ __launch_bounds__(256) void kEncCount(const float* __restrict__ X,
                                                 const float* __restrict__ Xs,
                                                 const float* __restrict__ W1,
                                                 float* __restrict__ h,
                                                 const int* __restrict__ dst,
                                                 const int* __restrict__ bassign,
                                                 int* cntn, int* cntb) {
  int bid = blockIdx.x, j = threadIdx.x;
  if (bid < NCB) {
    int t = bid * 256 + j;
    if (t < EE) atomicAdd(&cntn[dst[t]], 1);
    if (t < NN) atomicAdd(&cntb[bassign[t]], 1);
  } else {
    int r = (bid - NCB) * 4 + (j >> 6);     // wave-per-row
    int lane = j & 63, c0 = lane * 4;
    const float* x = (r < NN) ? (X + (size_t)r * 2) : (Xs + (size_t)(r - NN) * 2);
    float x0 = x[0], x1 = x[1];
    float4 wa = *(const float4*)(W1 + c0);
    float4 wb = *(const float4*)(W1 + DD + c0);
    float4 v;
    v.x = fmaxf(fmaf(x0, wa.x, x1 * wb.x), 0.f);
    v.y = fmaxf(fmaf(x0, wa.y, x1 * wb.y), 0.f);
    v.z = fmaxf(fmaf(x0, wa.z, x1 * wb.z), 0.f);
    v.w = fmaxf(fmaf(x0, wa.w, x1 * wb.w), 0.f);
    float ss = v.x * v.x + v.y * v.y + v.z * v.z + v.w * v.w;
    #pragma unroll
    for (int o = 1; o < 64; o <<= 1) ss += __shfl_xor(ss, o, 64);
    float inv = 1.f / fmaxf(sqrtf(ss), 1e-12f);
    v.x *= inv; v.y *= inv; v.z *= inv; v.w *= inv;
    *(float4*)(h + (size_t)r * DD + c0) = v;
  }
}

// ---------------------------------------------------------------- CSR scan
__global__ __launch_bounds__(1024) void kScan(const int* __restrict__ cntn,
                                              int* offn, int* curn,
                                              const int* __restrict__ cntb,
                                              int* offb, int* curb) {
  __shared__ int sums[1024];
  int t = threadIdx.x;
  const int CH = 20;  // 1024*20 = 20480 >= NN
  int base = t * CH;
  int local[CH];
  int s = 0;
  #pragma unroll
  for (int i = 0; i < CH; i++) {
    int idx = base + i;
    int v = (idx < NN) ? cntn[idx] : 0;
    local[i] = s;
    s += v;
  }
  sums[t] = s;
  __syncthreads();
  for (int o = 1; o < 1024; o <<= 1) {
    int x = (t >= o) ? sums[t - o] : 0;
    __syncthreads();
    sums[t] += x;
    __syncthreads();
  }
  int excl = sums[t] - s;
  #pragma unroll
  for (int i = 0; i < CH; i++) {
    int idx = base + i;
    if (idx < NN) {
      int o = excl + local[i];
      offn[idx] = o;
      curn[idx] = o;
    }
  }
  if (t == 1023) offn[NN] = sums[1023];
  // batch offsets: 64-lane shuffle scan (first wave)
  if (t < 64) {
    int v = cntb[t];
    int incl = v;
    #pragma unroll
    for (int o = 1; o < 64; o <<= 1) {
      int x = __shfl_up(incl, o, 64);
      if (t >= o) incl += x;
    }
    int excl2 = incl - v;
    offb[t] = excl2;
    curb[t] = excl2;
    if (t == 63) offb[BB] = incl;
  }
}

__global__ __launch_bounds__(256) void kScatter(const int* __restrict__ src,
                                                const int* __restrict__ dst,
                                                const float* __restrict__ w,
                                                const int* __restrict__ bassign,
                                                int* curn, int* curb,
                                                long long* sedge, int* snode) {
  int t = blockIdx.x * 256 + threadIdx.x;
  if (t < EE) {
    int d = dst[t];
    int p = atomicAdd(&curn[d], 1);
    unsigned long long e = (unsigned long long)(unsigned)src[t]
                         | ((unsigned long long)(unsigned)__float_as_int(w[t]) << 32);
    sedge[p] = (long long)e;
  }
  if (t < NN) {
    int b = bassign[t];
    int p = atomicAdd(&curb[b], 1);
    snode[p] = t;
  }
}

// ---------------------------------------------------------------- aggregation (XCD-sliced)
// 8 feature slices of 32 cols (128B = 1 line/row). slice = blockIdx&7 -> one slice
// per XCD under round-robin dispatch => per-XCD hot set 20064*128B = 2.56MB < 4MB L2.
// Block: 8 nodes x 32 lanes. nodeId < BB -> batch row (dst NN+nodeId), else edge node.
__global__ __launch_bounds__(256) void kAgg(const float* __restrict__ h,
                                            const int* __restrict__ offn,
                                            const long long* __restrict__ sedge,
                                            const int* __restrict__ offb,
                                            const int* __restrict__ snode,
                                            float* __restrict__ hnv) {
  int bid = blockIdx.x;
  int slice = bid & 7, group = bid >> 3;
  int g = threadIdx.x >> 5, c = threadIdx.x & 31;
  int nodeId = group * 8 + g;
  int col = slice * 32 + c;
  float acc = 0.f;
  if (nodeId < BB) {
    int s = offb[nodeId], e = offb[nodeId + 1];
    int i = s;
    for (; i + 3 < e; i += 4) {
      int n0 = __builtin_nontemporal_load(&snode[i]);
      int n1 = __builtin_nontemporal_load(&snode[i + 1]);
      int n2 = __builtin_nontemporal_load(&snode[i + 2]);
      int n3 = __builtin_nontemporal_load(&snode[i + 3]);
      float v0 = h[(size_t)n0 * DD + col];
      float v1 = h[(size_t)n1 * DD + col];
      float v2 = h[(size_t)n2 * DD + col];
      float v3 = h[(size_t)n3 * DD + col];
      acc += (v0 + v1) + (v2 + v3);
    }
    for (; i < e; i++) acc += h[(size_t)__builtin_nontemporal_load(&snode[i]) * DD + col];
    hnv[(size_t)(NN + nodeId) * DD + col] = acc;
  } else {
    int n = nodeId - BB;
    int s = offn[n], e = offn[n + 1];
    int i = s;
    for (; i + 3 < e; i += 4) {
      long long e0 = __builtin_nontemporal_load(&sedge[i]);
      long long e1 = __builtin_nontemporal_load(&sedge[i + 1]);
      long long e2 = __builtin_nontemporal_load(&sedge[i + 2]);
      long long e3 = __builtin_nontemporal_load(&sedge[i + 3]);
      float v0 = h[(size_t)(unsigned)(e0 & 0xffffffffLL) * DD + col];
      float v1 = h[(size_t)(unsigned)(e1 & 0xffffffffLL) * DD + col];
      float v2 = h[(size_t)(unsigned)(e2 & 0xffffffffLL) * DD + col];
      float v3 = h[(size_t)(unsigned)(e3 & 0xffffffffLL) * DD + col];
      acc = fmaf(__int_as_float((int)(e0 >> 32)), v0, acc);
      acc = fmaf(__int_as_float((int)(e1 >> 32)), v1, acc);
      acc = fmaf(__int_as_float((int)(e2 >> 32)), v2, acc);
      acc = fmaf(__int_as_float((int)(e3 >> 32)), v3, acc);
    }
    for (; i < e; i++) {
      long long e0 = __builtin_nontemporal_load(&sedge[i]);
      acc = fmaf(__int_as_float((int)(e0 >> 32)),
                 h[(size_t)(unsigned)(e0 & 0xffffffffLL) * DD + col], acc);
    }
    hnv[(size_t)n * DD + col] = acc;
  }
}

// ---------------------------------------------------------------- MFMA dual-GEMM + fused l2norm
// hOut[r,:] = l2norm( relu( sum_k A'[r,k]*B'[k,c] + lb[c] ) ), A' = [h | hnv] (K=512).
// Tile: 32 rows x 256 cols (full width) per block; 4 waves of 32x64; grid = 627 (exact).
#define TRU 32
#define KC 32
__global__ __launch_bounds__(256) void kUpdM(const float* __restrict__ A,
                                             const float* __restrict__ Av,
                                             const short* __restrict__ Bth,
                                             const short* __restrict__ Btl,
                                             const float* __restrict__ lb,
                                             float* __restrict__ out) {
  __shared__ __align__(16) short Ah[TRU][KC];
  __shared__ __align__(16) short Al[TRU][KC];
  __shared__ __align__(16) short Bh[DD][KC];
  __shared__ __align__(16) short Bl[DD][KC];
  __shared__ float ssq[4][TRU];
  const int t = threadIdx.x;
  const int rb = blockIdx.x * TRU;
  const int wid = t >> 6;
  const int lane = t & 63;
  const int wc = wid * 64;         // wave col offset (4 waves cover 256 cols)
  const int m16 = lane & 15;
  const int kg = lane >> 4;        // 0..3

  floatx4 acc[2][4];
  #pragma unroll
  for (int ct = 0; ct < 4; ct++) {
    float b = lb[wc + ct * 16 + m16];
    #pragma unroll
    for (int rt = 0; rt < 2; rt++) acc[rt][ct] = (floatx4){b, b, b, b};
  }

  for (int kc = 0; kc < 512 / KC; ++kc) {
    const int k0 = kc * KC;
    const float* src = (k0 < DD) ? (A + k0) : (Av + (k0 - DD));
    // ---- stage A (fp32 -> hi/lo bf16), 32 rows x 32 k = 256 float4 (1/thread)
    {
      int r = t >> 3;              // 0..31
      int q = t & 7;               // float4 index within row
      float4 v = *(const float4*)(src + (size_t)(rb + r) * DD + q * 4);
      short s0 = f2bf(v.x), s1 = f2bf(v.y), s2 = f2bf(v.z), s3 = f2bf(v.w);
      short l0 = f2bf(v.x - bf2f(s0)), l1 = f2bf(v.y - bf2f(s1));
      short l2 = f2bf(v.z - bf2f(s2)), l3 = f2bf(v.w - bf2f(s3));
      uint2 whi, wlo;
      whi.x = (unsigned short)s0 | ((unsigned)(unsigned short)s1 << 16);
      whi.y = (unsigned short)s2 | ((unsigned)(unsigned short)s3 << 16);
      wlo.x = (unsigned short)l0 | ((unsigned)(unsigned short)l1 << 16);
      wlo.y = (unsigned short)l2 | ((unsigned)(unsigned short)l3 << 16);
      *(uint2*)&Ah[r][q * 4] = whi;
      *(uint2*)&Al[r][q * 4] = wlo;
    }
    // ---- stage B (pre-split bf16, straight copy), 256 n x 32 k per plane
    #pragma unroll
    for (int it = 0; it < 4; ++it) {
      int idx = t + it * 256;      // 0..1023
      int n = idx >> 2;            // 0..255
      int sg = idx & 3;            // 16B segment
      *(uint4*)&Bh[n][sg * 8] = *((const uint4*)(Bth + (size_t)n * 512 + k0) + sg);
      *(uint4*)&Bl[n][sg * 8] = *((const uint4*)(Btl + (size_t)n * 512 + k0) + sg);
    }
    __syncthreads();
    // ---- fragments + MFMA
    short8 af[2], al_[2], bf_[4], bl_[4];
    #pragma unroll
    for (int rt = 0; rt < 2; rt++) {
      af[rt]  = *(const short8*)&Ah[rt * 16 + m16][kg * 8];
      al_[rt] = *(const short8*)&Al[rt * 16 + m16][kg * 8];
    }
    #pragma unroll
    for (int ct = 0; ct < 4; ct++) {
      bf_[ct] = *(const short8*)&Bh[wc + ct * 16 + m16][kg * 8];
      bl_[ct] = *(const short8*)&Bl[wc + ct * 16 + m16][kg * 8];
    }
    #pragma unroll
    for (int rt = 0; rt < 2; rt++)
      #pragma unroll
      for (int ct = 0; ct < 4; ct++) {
        acc[rt][ct] = __builtin_amdgcn_mfma_f32_16x16x32_bf16(af[rt], bf_[ct], acc[rt][ct], 0, 0, 0);
        acc[rt][ct] = __builtin_amdgcn_mfma_f32_16x16x32_bf16(af[rt], bl_[ct], acc[rt][ct], 0, 0, 0);
        acc[rt][ct] = __builtin_amdgcn_mfma_f32_16x16x32_bf16(al_[rt], bf_[ct], acc[rt][ct], 0, 0, 0);
      }
    __syncthreads();
  }
  // ---- epilogue: relu + row l2norm + store (C/D: col=lane&15, row=(lane>>4)*4+reg)
  float p[2][4];
  #pragma unroll
  for (int rt = 0; rt < 2; rt++)
    #pragma unroll
    for (int reg = 0; reg < 4; reg++) {
      float s = 0.f;
      #pragma unroll
      for (int ct = 0; ct < 4; ct++) {
        float x = fmaxf(acc[rt][ct][reg], 0.f);
        s = fmaf(x, x, s);
      }
      p[rt][reg] = s;
    }
  #pragma unroll
  for (int o = 1; o < 16; o <<= 1)
    #pragma unroll
    for (int rt = 0; rt < 2; rt++)
      #pragma unroll
      for (int reg = 0; reg < 4; reg++)
        p[rt][reg] += __shfl_xor(p[rt][reg], o, 64);
  if (m16 == 0) {
    #pragma unroll
    for (int rt = 0; rt < 2; rt++)
      #pragma unroll
      for (int reg = 0; reg < 4; reg++)
        ssq[wid][rt * 16 + kg * 4 + reg] = p[rt][reg];
  }
  __syncthreads();
  #pragma unroll
  for (int rt = 0; rt < 2; rt++) {
    #pragma unroll
    for (int reg = 0; reg < 4; reg++) {
      int row = rt * 16 + kg * 4 + reg;
      float ss = ssq[0][row] + ssq[1][row] + ssq[2][row] + ssq[3][row];
      float inv = 1.f / fmaxf(sqrtf(ss), 1e-12f);
      #pragma unroll
      for (int ct = 0; ct < 4; ct++) {
        int col = wc + ct * 16 + m16;
        out[(size_t)(rb + row) * DD + col] = fmaxf(acc[rt][ct][reg], 0.f) * inv;
      }
    }
  }
}

// ---------------------------------------------------------------- decode
__global__ __launch_bounds__(256) void kDec(const float* __restrict__ h,
                                            const int* __restrict__ aidx,
                                            const float* __restrict__ W4,
                                            const float* __restrict__ W5,
                                            float* __restrict__ Q) {
  __shared__ float tmp[4];
  int b = blockIdx.x, j = threadIdx.x;
  float s = blockSum256(h[(size_t)(NN + b) * DD + j] * W4[j], tmp);
  int a = aidx[b];
  float za = h[(size_t)a * DD + j];
  float q = blockSum256(fmaxf(za * s, 0.f) * W5[j], tmp);
  if (j == 0) Q[b] = q;
}

// ---------------------------------------------------------------- launcher
extern "C" void kernel_launch(void* const* d_in, const int* in_sizes, int n_in,
                              void* d_out, int out_size, void* d_ws, size_t ws_size,
                              hipStream_t stream) {
  (void)in_sizes; (void)n_in; (void)out_size; (void)ws_size;
  const int*   edge_src = (const int*)d_in[0];
  const int*   edge_dst = (const int*)d_in[1];
  const float* edge_w   = (const float*)d_in[2];
  const int*   bassign  = (const int*)d_in[3];
  const int*   aidx     = (const int*)d_in[4];
  const float* Xf       = (const float*)d_in[5];
  const float* Xs       = (const float*)d_in[6];
  const float* W1       = (const float*)d_in[7];
  const float* W2       = (const float*)d_in[8];
  const float* W3       = (const float*)d_in[9];
  const float* linW     = (const float*)d_in[10];
  const float* linB     = (const float*)d_in[11];
  const float* W4       = (const float*)d_in[12];
  const float* W5       = (const float*)d_in[13];
  float* Q = (float*)d_out;

  char* base = (char*)d_ws;
  const size_t NB = (size_t)NT * DD * 4;   // rows include hs
  float* hA   = (float*)(base);
  float* hnv  = (float*)(base + NB);
  float* hB   = (float*)(base + 2 * NB);
  size_t o = 3 * NB;
  short* Bth  = (short*)(base + o); o += (size_t)DD * 512 * 2;
  short* Btl  = (short*)(base + o); o += (size_t)DD * 512 * 2;
  long long* sedge = (long long*)(base + o); o += (size_t)EE * 8;
  int*   snode= (int*)(base + o);   o += (size_t)NN * 4;
  int*   cntn = (int*)(base + o);   o += (size_t)NN * 4;
  int*   cntb = (int*)(base + o);   o += (size_t)BB * 4;   // contiguous with cntn
  int*   offn = (int*)(base + o);   o += (size_t)(NN + 4) * 4;
  int*   offb = (int*)(base + o);   o += (size_t)(BB + 4) * 4;
  int*   curn = (int*)(base + o);   o += (size_t)NN * 4;
  int*   curb = (int*)(base + o);   o += (size_t)BB * 4;

  hipMemsetAsync(cntn, 0, (size_t)(NN + BB) * 4, stream);

  kM<<<512, 256, 0, stream>>>(W2, W3, linW, Bth, Btl);
  kEncCount<<<NCB + NT / 4, 256, 0, stream>>>(Xf, Xs, W1, hA,
                                              edge_dst, bassign, cntn, cntb);
  kScan<<<1, 1024, 0, stream>>>(cntn, offn, curn, cntb, offb, curb);
  kScatter<<<(EE + 255) / 256, 256, 0, stream>>>(edge_src, edge_dst, edge_w, bassign,
                                                 curn, curb, sedge, snode);
  float* hc = hA;
  float* hn = hB;
  for (int d = 0; d < DEPTH; d++) {
    kAgg<<<NT, 256, 0, stream>>>(hc, offn, sedge, offb, snode, hnv);
    kUpdM<<<NT / TRU, 256, 0, stream>>>(hc, hnv, Bth, Btl, linB, hn);
    float* sw2 = hc; hc = hn; hn = sw2;
  }
  kDec<<<BB, 256, 0, stream>>>(hc, aidx, W4, W5, Q);
}

// Round 7
// 502.103 us; speedup vs baseline: 1.1706x; 1.1706x over previous
//
#include <hip/hip_runtime.h>

#define NN 20000
#define EE 320000
#define BB 64
#define DD 256
#define DEPTH 3
#define NT (NN + BB)   // h rows + hs rows appended (NT = 20064 = 32*627 = 8*2508)

typedef __attribute__((ext_vector_type(8))) short short8;
typedef __attribute__((ext_vector_type(4))) float floatx4;

// ---------------------------------------------------------------- bf16 split helpers
__device__ __forceinline__ short f2bf(float x) {
  union { float f; unsigned u; } v; v.f = x;
  unsigned r = v.u + 0x7fffu + ((v.u >> 16) & 1u);  // RNE
  return (short)(r >> 16);
}
__device__ __forceinline__ float bf2f(short s) {
  union { unsigned u; float f; } v; v.u = ((unsigned)(unsigned short)s) << 16;
  return v.f;
}

// ---------------------------------------------------------------- reductions
__device__ __forceinline__ float blockSum256(float v, float* tmp) {
  #pragma unroll
  for (int o = 32; o > 0; o >>= 1) v += __shfl_down(v, o, 64);
  if ((threadIdx.x & 63) == 0) tmp[threadIdx.x >> 6] = v;
  __syncthreads();
  float r = tmp[0] + tmp[1] + tmp[2] + tmp[3];
  __syncthreads();
  return r;
}

// ---------------------------------------------------------------- M2/M3 -> split transposed B
// M2 = W2 @ linW[0:256,:], M3 = W3 @ linW[256:512,:]
// B'[k][n]: rows 0..255 = M2, 256..511 = M3. Stored as Bt_hi/lo[n][k] bf16 [256][512].
__global__ __launch_bounds__(256) void kM(const float* __restrict__ W2,
                                          const float* __restrict__ W3,
                                          const float* __restrict__ linW,
                                          short* __restrict__ Bth,
                                          short* __restrict__ Btl) {
  int i = blockIdx.x & 255;
  bool second = blockIdx.x >= 256;
  const float* W = second ? W3 : W2;
  const float* L = linW + (second ? DD * DD : 0);
  int j = threadIdx.x;
  float acc = 0.f;
  #pragma unroll 4
  for (int k = 0; k < DD; k++) acc = fmaf(W[i * DD + k], L[k * DD + j], acc);
  short hi = f2bf(acc);
  short lo = f2bf(acc - bf2f(hi));
  int kk = second ? (DD + i) : i;
  Bth[(size_t)j * 512 + kk] = hi;
  Btl[(size_t)j * 512 + kk] = lo;
}

// ---------------------------------------------------------------- count (first) + encode (wave-per-row)
#define NCB ((EE + 255) / 256)   // 1250 count blocks, scheduled first
__global__ __launch_bounds__(256) void kEncCount(const float* __restrict__ X,
                                                 const float* __restrict__ Xs,
                                                 const float* __restrict__ W1,
                                                 float* __restrict__ h,
                                                 const int* __restrict__ dst,
                                                 const int* __restrict__ bassign,
                                                 int* cntn, int* cntb) {
  int bid = blockIdx.x, j = threadIdx.x;
  if (bid < NCB) {
    int t = bid * 256 + j;
    if (t < EE) atomicAdd(&cntn[dst[t]], 1);
    if (t < NN) atomicAdd(&cntb[bassign[t]], 1);
  } else {
    int r = (bid - NCB) * 4 + (j >> 6);     // wave-per-row
    int lane = j & 63, c0 = lane * 4;
    const float* x = (r < NN) ? (X + (size_t)r * 2) : (Xs + (size_t)(r - NN) * 2);
    float x0 = x[0], x1 = x[1];
    float4 wa = *(const float4*)(W1 + c0);
    float4 wb = *(const float4*)(W1 + DD + c0);
    float4 v;
    v.x = fmaxf(fmaf(x0, wa.x, x1 * wb.x), 0.f);
    v.y = fmaxf(fmaf(x0, wa.y, x1 * wb.y), 0.f);
    v.z = fmaxf(fmaf(x0, wa.z, x1 * wb.z), 0.f);
    v.w = fmaxf(fmaf(x0, wa.w, x1 * wb.w), 0.f);
    float ss = v.x * v.x + v.y * v.y + v.z * v.z + v.w * v.w;
    #pragma unroll
    for (int o = 1; o < 64; o <<= 1) ss += __shfl_xor(ss, o, 64);
    float inv = 1.f / fmaxf(sqrtf(ss), 1e-12f);
    v.x *= inv; v.y *= inv; v.z *= inv; v.w *= inv;
    *(float4*)(h + (size_t)r * DD + c0) = v;
  }
}

// ---------------------------------------------------------------- CSR scan
__global__ __launch_bounds__(1024) void kScan(const int* __restrict__ cntn,
                                              int* offn, int* curn,
                                              const int* __restrict__ cntb,
                                              int* offb, int* curb) {
  __shared__ int sums[1024];
  int t = threadIdx.x;
  const int CH = 20;  // 1024*20 = 20480 >= NN
  int base = t * CH;
  int local[CH];
  int s = 0;
  #pragma unroll
  for (int i = 0; i < CH; i++) {
    int idx = base + i;
    int v = (idx < NN) ? cntn[idx] : 0;
    local[i] = s;
    s += v;
  }
  sums[t] = s;
  __syncthreads();
  for (int o = 1; o < 1024; o <<= 1) {
    int x = (t >= o) ? sums[t - o] : 0;
    __syncthreads();
    sums[t] += x;
    __syncthreads();
  }
  int excl = sums[t] - s;
  #pragma unroll
  for (int i = 0; i < CH; i++) {
    int idx = base + i;
    if (idx < NN) {
      int o = excl + local[i];
      offn[idx] = o;
      curn[idx] = o;
    }
  }
  if (t == 1023) offn[NN] = sums[1023];
  // batch offsets: 64-lane shuffle scan (first wave)
  if (t < 64) {
    int v = cntb[t];
    int incl = v;
    #pragma unroll
    for (int o = 1; o < 64; o <<= 1) {
      int x = __shfl_up(incl, o, 64);
      if (t >= o) incl += x;
    }
    int excl2 = incl - v;
    offb[t] = excl2;
    curb[t] = excl2;
    if (t == 63) offb[BB] = incl;
  }
}

__global__ __launch_bounds__(256) void kScatter(const int* __restrict__ src,
                                                const int* __restrict__ dst,
                                                const float* __restrict__ w,
                                                const int* __restrict__ bassign,
                                                int* curn, int* curb,
                                                long long* sedge, int* snode) {
  int t = blockIdx.x * 256 + threadIdx.x;
  if (t < EE) {
    int d = dst[t];
    int p = atomicAdd(&curn[d], 1);
    unsigned long long e = (unsigned long long)(unsigned)src[t]
                         | ((unsigned long long)(unsigned)__float_as_int(w[t]) << 32);
    sedge[p] = (long long)e;
  }
  if (t < NN) {
    int b = bassign[t];
    int p = atomicAdd(&curb[b], 1);
    snode[p] = t;
  }
}

// ---------------------------------------------------------------- aggregation (XCD-sliced)
// 8 feature slices of 32 cols (128B = 1 line/row). slice = blockIdx&7 -> one slice
// per XCD under round-robin dispatch => per-XCD h hot set 20064*128B = 2.56MB.
// Plain (cached) loads on sedge/snode: the 8x re-read stream must stay in L2 —
// nt loads bypassing L2 put ~900cyc HBM latency in every chain (round-6 regression).
__global__ __launch_bounds__(256) void kAgg(const float* __restrict__ h,
                                            const int* __restrict__ offn,
                                            const long long* __restrict__ sedge,
                                            const int* __restrict__ offb,
                                            const int* __restrict__ snode,
                                            float* __restrict__ hnv) {
  int bid = blockIdx.x;
  int slice = bid & 7, group = bid >> 3;
  int g = threadIdx.x >> 5, c = threadIdx.x & 31;
  int nodeId = group * 8 + g;
  int col = slice * 32 + c;
  float acc = 0.f;
  if (nodeId < BB) {
    int s = offb[nodeId], e = offb[nodeId + 1];
    int i = s;
    for (; i + 3 < e; i += 4) {
      int n0 = snode[i];
      int n1 = snode[i + 1];
      int n2 = snode[i + 2];
      int n3 = snode[i + 3];
      float v0 = h[(size_t)n0 * DD + col];
      float v1 = h[(size_t)n1 * DD + col];
      float v2 = h[(size_t)n2 * DD + col];
      float v3 = h[(size_t)n3 * DD + col];
      acc += (v0 + v1) + (v2 + v3);
    }
    for (; i < e; i++) acc += h[(size_t)snode[i] * DD + col];
    hnv[(size_t)(NN + nodeId) * DD + col] = acc;
  } else {
    int n = nodeId - BB;
    int s = offn[n], e = offn[n + 1];
    int i = s;
    for (; i + 3 < e; i += 4) {
      long long e0 = sedge[i];
      long long e1 = sedge[i + 1];
      long long e2 = sedge[i + 2];
      long long e3 = sedge[i + 3];
      float v0 = h[(size_t)(unsigned)(e0 & 0xffffffffLL) * DD + col];
      float v1 = h[(size_t)(unsigned)(e1 & 0xffffffffLL) * DD + col];
      float v2 = h[(size_t)(unsigned)(e2 & 0xffffffffLL) * DD + col];
      float v3 = h[(size_t)(unsigned)(e3 & 0xffffffffLL) * DD + col];
      acc = fmaf(__int_as_float((int)(e0 >> 32)), v0, acc);
      acc = fmaf(__int_as_float((int)(e1 >> 32)), v1, acc);
      acc = fmaf(__int_as_float((int)(e2 >> 32)), v2, acc);
      acc = fmaf(__int_as_float((int)(e3 >> 32)), v3, acc);
    }
    for (; i < e; i++) {
      long long e0 = sedge[i];
      acc = fmaf(__int_as_float((int)(e0 >> 32)),
                 h[(size_t)(unsigned)(e0 & 0xffffffffLL) * DD + col], acc);
    }
    hnv[(size_t)n * DD + col] = acc;
  }
}

// ---------------------------------------------------------------- MFMA dual-GEMM + fused l2norm
// hOut[r,:] = l2norm( relu( sum_k A'[r,k]*B'[k,c] + lb[c] ) ), A' = [h | hnv] (K=512).
// Tile: 32 rows x 256 cols (full width) per block; 4 waves of 32x64; grid = 627 (exact).
#define TRU 32
#define KC 32
__global__ __launch_bounds__(256) void kUpdM(const float* __restrict__ A,
                                             const float* __restrict__ Av,
                                             const short* __restrict__ Bth,
                                             const short* __restrict__ Btl,
                                             const float* __restrict__ lb,
                                             float* __restrict__ out) {
  __shared__ __align__(16) short Ah[TRU][KC];
  __shared__ __align__(16) short Al[TRU][KC];
  __shared__ __align__(16) short Bh[DD][KC];
  __shared__ __align__(16) short Bl[DD][KC];
  __shared__ float ssq[4][TRU];
  const int t = threadIdx.x;
  const int rb = blockIdx.x * TRU;
  const int wid = t >> 6;
  const int lane = t & 63;
  const int wc = wid * 64;         // wave col offset (4 waves cover 256 cols)
  const int m16 = lane & 15;
  const int kg = lane >> 4;        // 0..3

  floatx4 acc[2][4];
  #pragma unroll
  for (int ct = 0; ct < 4; ct++) {
    float b = lb[wc + ct * 16 + m16];
    #pragma unroll
    for (int rt = 0; rt < 2; rt++) acc[rt][ct] = (floatx4){b, b, b, b};
  }

  for (int kc = 0; kc < 512 / KC; ++kc) {
    const int k0 = kc * KC;
    const float* src = (k0 < DD) ? (A + k0) : (Av + (k0 - DD));
    // ---- stage A (fp32 -> hi/lo bf16), 32 rows x 32 k = 256 float4 (1/thread)
    {
      int r = t >> 3;              // 0..31
      int q = t & 7;               // float4 index within row
      float4 v = *(const float4*)(src + (size_t)(rb + r) * DD + q * 4);
      short s0 = f2bf(v.x), s1 = f2bf(v.y), s2 = f2bf(v.z), s3 = f2bf(v.w);
      short l0 = f2bf(v.x - bf2f(s0)), l1 = f2bf(v.y - bf2f(s1));
      short l2 = f2bf(v.z - bf2f(s2)), l3 = f2bf(v.w - bf2f(s3));
      uint2 whi, wlo;
      whi.x = (unsigned short)s0 | ((unsigned)(unsigned short)s1 << 16);
      whi.y = (unsigned short)s2 | ((unsigned)(unsigned short)s3 << 16);
      wlo.x = (unsigned short)l0 | ((unsigned)(unsigned short)l1 << 16);
      wlo.y = (unsigned short)l2 | ((unsigned)(unsigned short)l3 << 16);
      *(uint2*)&Ah[r][q * 4] = whi;
      *(uint2*)&Al[r][q * 4] = wlo;
    }
    // ---- stage B (pre-split bf16, straight copy), 256 n x 32 k per plane
    #pragma unroll
    for (int it = 0; it < 4; ++it) {
      int idx = t + it * 256;      // 0..1023
      int n = idx >> 2;            // 0..255
      int sg = idx & 3;            // 16B segment
      *(uint4*)&Bh[n][sg * 8] = *((const uint4*)(Bth + (size_t)n * 512 + k0) + sg);
      *(uint4*)&Bl[n][sg * 8] = *((const uint4*)(Btl + (size_t)n * 512 + k0) + sg);
    }
    __syncthreads();
    // ---- fragments + MFMA
    short8 af[2], al_[2], bf_[4], bl_[4];
    #pragma unroll
    for (int rt = 0; rt < 2; rt++) {
      af[rt]  = *(const short8*)&Ah[rt * 16 + m16][kg * 8];
      al_[rt] = *(const short8*)&Al[rt * 16 + m16][kg * 8];
    }
    #pragma unroll
    for (int ct = 0; ct < 4; ct++) {
      bf_[ct] = *(const short8*)&Bh[wc + ct * 16 + m16][kg * 8];
      bl_[ct] = *(const short8*)&Bl[wc + ct * 16 + m16][kg * 8];
    }
    #pragma unroll
    for (int rt = 0; rt < 2; rt++)
      #pragma unroll
      for (int ct = 0; ct < 4; ct++) {
        acc[rt][ct] = __builtin_amdgcn_mfma_f32_16x16x32_bf16(af[rt], bf_[ct], acc[rt][ct], 0, 0, 0);
        acc[rt][ct] = __builtin_amdgcn_mfma_f32_16x16x32_bf16(af[rt], bl_[ct], acc[rt][ct], 0, 0, 0);
        acc[rt][ct] = __builtin_amdgcn_mfma_f32_16x16x32_bf16(al_[rt], bf_[ct], acc[rt][ct], 0, 0, 0);
      }
    __syncthreads();
  }
  // ---- epilogue: relu + row l2norm + store (C/D: col=lane&15, row=(lane>>4)*4+reg)
  float p[2][4];
  #pragma unroll
  for (int rt = 0; rt < 2; rt++)
    #pragma unroll
    for (int reg = 0; reg < 4; reg++) {
      float s = 0.f;
      #pragma unroll
      for (int ct = 0; ct < 4; ct++) {
        float x = fmaxf(acc[rt][ct][reg], 0.f);
        s = fmaf(x, x, s);
      }
      p[rt][reg] = s;
    }
  #pragma unroll
  for (int o = 1; o < 16; o <<= 1)
    #pragma unroll
    for (int rt = 0; rt < 2; rt++)
      #pragma unroll
      for (int reg = 0; reg < 4; reg++)
        p[rt][reg] += __shfl_xor(p[rt][reg], o, 64);
  if (m16 == 0) {
    #pragma unroll
    for (int rt = 0; rt < 2; rt++)
      #pragma unroll
      for (int reg = 0; reg < 4; reg++)
        ssq[wid][rt * 16 + kg * 4 + reg] = p[rt][reg];
  }
  __syncthreads();
  #pragma unroll
  for (int rt = 0; rt < 2; rt++) {
    #pragma unroll
    for (int reg = 0; reg < 4; reg++) {
      int row = rt * 16 + kg * 4 + reg;
      float ss = ssq[0][row] + ssq[1][row] + ssq[2][row] + ssq[3][row];
      float inv = 1.f / fmaxf(sqrtf(ss), 1e-12f);
      #pragma unroll
      for (int ct = 0; ct < 4; ct++) {
        int col = wc + ct * 16 + m16;
        out[(size_t)(rb + row) * DD + col] = fmaxf(acc[rt][ct][reg], 0.f) * inv;
      }
    }
  }
}

// ---------------------------------------------------------------- decode
__global__ __launch_bounds__(256) void kDec(const float* __restrict__ h,
                                            const int* __restrict__ aidx,
                                            const float* __restrict__ W4,
                                            const float* __restrict__ W5,
                                            float* __restrict__ Q) {
  __shared__ float tmp[4];
  int b = blockIdx.x, j = threadIdx.x;
  float s = blockSum256(h[(size_t)(NN + b) * DD + j] * W4[j], tmp);
  int a = aidx[b];
  float za = h[(size_t)a * DD + j];
  float q = blockSum256(fmaxf(za * s, 0.f) * W5[j], tmp);
  if (j == 0) Q[b] = q;
}

// ---------------------------------------------------------------- launcher
extern "C" void kernel_launch(void* const* d_in, const int* in_sizes, int n_in,
                              void* d_out, int out_size, void* d_ws, size_t ws_size,
                              hipStream_t stream) {
  (void)in_sizes; (void)n_in; (void)out_size; (void)ws_size;
  const int*   edge_src = (const int*)d_in[0];
  const int*   edge_dst = (const int*)d_in[1];
  const float* edge_w   = (const float*)d_in[2];
  const int*   bassign  = (const int*)d_in[3];
  const int*   aidx     = (const int*)d_in[4];
  const float* Xf       = (const float*)d_in[5];
  const float* Xs       = (const float*)d_in[6];
  const float* W1       = (const float*)d_in[7];
  const float* W2       = (const float*)d_in[8];
  const float* W3       = (const float*)d_in[9];
  const float* linW     = (const float*)d_in[10];
  const float* linB     = (const float*)d_in[11];
  const float* W4       = (const float*)d_in[12];
  const float* W5       = (const float*)d_in[13];
  float* Q = (float*)d_out;

  char* base = (char*)d_ws;
  const size_t NB = (size_t)NT * DD * 4;   // rows include hs
  float* hA   = (float*)(base);
  float* hnv  = (float*)(base + NB);
  float* hB   = (float*)(base + 2 * NB);
  size_t o = 3 * NB;
  short* Bth  = (short*)(base + o); o += (size_t)DD * 512 * 2;
  short* Btl  = (short*)(base + o); o += (size_t)DD * 512 * 2;
  long long* sedge = (long long*)(base + o); o += (size_t)EE * 8;
  int*   snode= (int*)(base + o);   o += (size_t)NN * 4;
  int*   cntn = (int*)(base + o);   o += (size_t)NN * 4;
  int*   cntb = (int*)(base + o);   o += (size_t)BB * 4;   // contiguous with cntn
  int*   offn = (int*)(base + o);   o += (size_t)(NN + 4) * 4;
  int*   offb = (int*)(base + o);   o += (size_t)(BB + 4) * 4;
  int*   curn = (int*)(base + o);   o += (size_t)NN * 4;
  int*   curb = (int*)(base + o);   o += (size_t)BB * 4;

  hipMemsetAsync(cntn, 0, (size_t)(NN + BB) * 4, stream);

  kM<<<512, 256, 0, stream>>>(W2, W3, linW, Bth, Btl);
  kEncCount<<<NCB + NT / 4, 256, 0, stream>>>(Xf, Xs, W1, hA,
                                              edge_dst, bassign, cntn, cntb);
  kScan<<<1, 1024, 0, stream>>>(cntn, offn, curn, cntb, offb, curb);
  kScatter<<<(EE + 255) / 256, 256, 0, stream>>>(edge_src, edge_dst, edge_w, bassign,
                                                 curn, curb, sedge, snode);
  float* hc = hA;
  float* hn = hB;
  for (int d = 0; d < DEPTH; d++) {
    kAgg<<<NT, 256, 0, stream>>>(hc, offn, sedge, offb, snode, hnv);
    kUpdM<<<NT / TRU, 256, 0, stream>>>(hc, hnv, Bth, Btl, linB, hn);
    float* sw2 = hc; hc = hn; hn = sw2;
  }
  kDec<<<BB, 256, 0, stream>>>(hc, aidx, W4, W5, Q);
}

// Round 8
// 464.587 us; speedup vs baseline: 1.2652x; 1.0808x over previous
//
#include <hip/hip_runtime.h>

#define NN 20000
#define EE 320000
#define BB 64
#define DD 256
#define DEPTH 3
#define NT (NN + BB)   // h rows + hs rows appended (NT = 20064 = 32*627 = 4*5016)

typedef __attribute__((ext_vector_type(8))) short short8;
typedef __attribute__((ext_vector_type(4))) float floatx4;

// ---------------------------------------------------------------- bf16 split helpers
__device__ __forceinline__ short f2bf(float x) {
  union { float f; unsigned u; } v; v.f = x;
  unsigned r = v.u + 0x7fffu + ((v.u >> 16) & 1u);  // RNE
  return (short)(r >> 16);
}
__device__ __forceinline__ float bf2f(short s) {
  union { unsigned u; float f; } v; v.u = ((unsigned)(unsigned short)s) << 16;
  return v.f;
}

// ---------------------------------------------------------------- reductions
__device__ __forceinline__ float blockSum256(float v, float* tmp) {
  #pragma unroll
  for (int o = 32; o > 0; o >>= 1) v += __shfl_down(v, o, 64);
  if ((threadIdx.x & 63) == 0) tmp[threadIdx.x >> 6] = v;
  __syncthreads();
  float r = tmp[0] + tmp[1] + tmp[2] + tmp[3];
  __syncthreads();
  return r;
}

// ---------------------------------------------------------------- M2/M3 -> split transposed B
__global__ __launch_bounds__(256) void kM(const float* __restrict__ W2,
                                          const float* __restrict__ W3,
                                          const float* __restrict__ linW,
                                          short* __restrict__ Bth,
                                          short* __restrict__ Btl) {
  int i = blockIdx.x & 255;
  bool second = blockIdx.x >= 256;
  const float* W = second ? W3 : W2;
  const float* L = linW + (second ? DD * DD : 0);
  int j = threadIdx.x;
  float acc = 0.f;
  #pragma unroll 4
  for (int k = 0; k < DD; k++) acc = fmaf(W[i * DD + k], L[k * DD + j], acc);
  short hi = f2bf(acc);
  short lo = f2bf(acc - bf2f(hi));
  int kk = second ? (DD + i) : i;
  Bth[(size_t)j * 512 + kk] = hi;
  Btl[(size_t)j * 512 + kk] = lo;
}

// ---------------------------------------------------------------- count (first) + encode (wave-per-row)
#define NCB ((EE + 255) / 256)   // 1250 count blocks, scheduled first
__global__ __launch_bounds__(256) void kEncCount(const float* __restrict__ X,
                                                 const float* __restrict__ Xs,
                                                 const float* __restrict__ W1,
                                                 float* __restrict__ h,
                                                 const int* __restrict__ dst,
                                                 const int* __restrict__ bassign,
                                                 int* cntn, int* cntb) {
  int bid = blockIdx.x, j = threadIdx.x;
  if (bid < NCB) {
    int t = bid * 256 + j;
    if (t < EE) atomicAdd(&cntn[dst[t]], 1);
    if (t < NN) atomicAdd(&cntb[bassign[t]], 1);
  } else {
    int r = (bid - NCB) * 4 + (j >> 6);     // wave-per-row
    int lane = j & 63, c0 = lane * 4;
    const float* x = (r < NN) ? (X + (size_t)r * 2) : (Xs + (size_t)(r - NN) * 2);
    float x0 = x[0], x1 = x[1];
    float4 wa = *(const float4*)(W1 + c0);
    float4 wb = *(const float4*)(W1 + DD + c0);
    float4 v;
    v.x = fmaxf(fmaf(x0, wa.x, x1 * wb.x), 0.f);
    v.y = fmaxf(fmaf(x0, wa.y, x1 * wb.y), 0.f);
    v.z = fmaxf(fmaf(x0, wa.z, x1 * wb.z), 0.f);
    v.w = fmaxf(fmaf(x0, wa.w, x1 * wb.w), 0.f);
    float ss = v.x * v.x + v.y * v.y + v.z * v.z + v.w * v.w;
    #pragma unroll
    for (int o = 1; o < 64; o <<= 1) ss += __shfl_xor(ss, o, 64);
    float inv = 1.f / fmaxf(sqrtf(ss), 1e-12f);
    v.x *= inv; v.y *= inv; v.z *= inv; v.w *= inv;
    *(float4*)(h + (size_t)r * DD + c0) = v;
  }
}

// ---------------------------------------------------------------- CSR scan
__global__ __launch_bounds__(1024) void kScan(const int* __restrict__ cntn,
                                              int* offn, int* curn,
                                              const int* __restrict__ cntb,
                                              int* offb, int* curb) {
  __shared__ int sums[1024];
  int t = threadIdx.x;
  const int CH = 20;  // 1024*20 = 20480 >= NN
  int base = t * CH;
  int local[CH];
  int s = 0;
  #pragma unroll
  for (int i = 0; i < CH; i++) {
    int idx = base + i;
    int v = (idx < NN) ? cntn[idx] : 0;
    local[i] = s;
    s += v;
  }
  sums[t] = s;
  __syncthreads();
  for (int o = 1; o < 1024; o <<= 1) {
    int x = (t >= o) ? sums[t - o] : 0;
    __syncthreads();
    sums[t] += x;
    __syncthreads();
  }
  int excl = sums[t] - s;
  #pragma unroll
  for (int i = 0; i < CH; i++) {
    int idx = base + i;
    if (idx < NN) {
      int o = excl + local[i];
      offn[idx] = o;
      curn[idx] = o;
    }
  }
  if (t == 1023) offn[NN] = sums[1023];
  // batch offsets: 64-lane shuffle scan (first wave)
  if (t < 64) {
    int v = cntb[t];
    int incl = v;
    #pragma unroll
    for (int o = 1; o < 64; o <<= 1) {
      int x = __shfl_up(incl, o, 64);
      if (t >= o) incl += x;
    }
    int excl2 = incl - v;
    offb[t] = excl2;
    curb[t] = excl2;
    if (t == 63) offb[BB] = incl;
  }
}

__global__ __launch_bounds__(256) void kScatter(const int* __restrict__ src,
                                                const int* __restrict__ dst,
                                                const float* __restrict__ w,
                                                const int* __restrict__ bassign,
                                                int* curn, int* curb,
                                                long long* sedge, int* snode) {
  int t = blockIdx.x * 256 + threadIdx.x;
  if (t < EE) {
    int d = dst[t];
    int p = atomicAdd(&curn[d], 1);
    unsigned long long e = (unsigned long long)(unsigned)src[t]
                         | ((unsigned long long)(unsigned)__float_as_int(w[t]) << 32);
    sedge[p] = (long long)e;
  }
  if (t < NN) {
    int b = bassign[t];
    int p = atomicAdd(&curb[b], 1);
    snode[p] = t;
  }
}

// ---------------------------------------------------------------- aggregation (XCD-sliced, LDS-staged edges)
// 8 feature slices of 32 cols; slice = blockIdx&7 -> per-XCD h hot set = 2.56MB (L2-resident).
// Block = 4 waves = 4 consecutive nodes of one slice. Each wave: 64 lanes = 2 edges x 32 cols
// (uniform loop bounds per wave). Edge lists (contiguous CSR range of the block's 4 nodes)
// are cooperatively staged into LDS -> inner chain is ds_read (broadcast) + one L2 gather.
#define ECAP 1024   // staged edges per chunk (8 KB)
__global__ __launch_bounds__(256) void kAgg(const float* __restrict__ h,
                                            const int* __restrict__ offn,
                                            const long long* __restrict__ sedge,
                                            const int* __restrict__ offb,
                                            const int* __restrict__ snode,
                                            float* __restrict__ hnv) {
  __shared__ __align__(16) long long Led[ECAP];
  int bid = blockIdx.x;
  int slice = bid & 7, group = bid >> 3;      // group 0..5015
  int t = threadIdx.x;
  int w = t >> 6, lane = t & 63;
  int sub = lane >> 5, c = lane & 31;
  int col = slice * 32 + c;
  float acc = 0.f;

  if (group < 16) {
    // ---- batch rows: nodes 0..63, snode index list (weight 1)
    int b0 = group * 4;
    int s0 = offb[b0], e0 = offb[b0 + 4];
    int sW = offb[b0 + w], eW = offb[b0 + w + 1];
    int* Li = (int*)Led;
    for (int base = s0; base < e0; base += 2 * ECAP) {
      int cnt = min(e0 - base, 2 * ECAP);
      __syncthreads();
      for (int i = t; i < cnt; i += 256) Li[i] = snode[base + i];
      __syncthreads();
      int lo = max(sW, base), hi = min(eW, base + cnt);
      int i = lo + sub;
      for (; i + 6 < hi; i += 8) {
        int n0 = Li[i - base],     n1 = Li[i + 2 - base];
        int n2 = Li[i + 4 - base], n3 = Li[i + 6 - base];
        float v0 = h[(size_t)n0 * DD + col];
        float v1 = h[(size_t)n1 * DD + col];
        float v2 = h[(size_t)n2 * DD + col];
        float v3 = h[(size_t)n3 * DD + col];
        acc += (v0 + v1) + (v2 + v3);
      }
      for (; i < hi; i += 2) acc += h[(size_t)Li[i - base] * DD + col];
    }
    acc += __shfl_xor(acc, 32, 64);
    if (sub == 0) hnv[(size_t)(NN + b0 + w) * DD + col] = acc;
  } else {
    // ---- edge nodes
    int first = group * 4 - BB;                // node range [first, first+4)
    int s0 = offn[first], e0 = offn[first + 4];
    int sW = offn[first + w], eW = offn[first + w + 1];
    for (int base = s0; base < e0; base += ECAP) {
      int cnt = min(e0 - base, ECAP);
      __syncthreads();
      for (int i = t; i < cnt; i += 256) Led[i] = sedge[base + i];
      __syncthreads();
      int lo = max(sW, base), hi = min(eW, base + cnt);
      int i = lo + sub;
      for (; i + 6 < hi; i += 8) {
        long long e0v = Led[i - base],     e1v = Led[i + 2 - base];
        long long e2v = Led[i + 4 - base], e3v = Led[i + 6 - base];
        float v0 = h[(size_t)(unsigned)(e0v & 0xffffffffLL) * DD + col];
        float v1 = h[(size_t)(unsigned)(e1v & 0xffffffffLL) * DD + col];
        float v2 = h[(size_t)(unsigned)(e2v & 0xffffffffLL) * DD + col];
        float v3 = h[(size_t)(unsigned)(e3v & 0xffffffffLL) * DD + col];
        acc = fmaf(__int_as_float((int)(e0v >> 32)), v0, acc);
        acc = fmaf(__int_as_float((int)(e1v >> 32)), v1, acc);
        acc = fmaf(__int_as_float((int)(e2v >> 32)), v2, acc);
        acc = fmaf(__int_as_float((int)(e3v >> 32)), v3, acc);
      }
      for (; i < hi; i += 2) {
        long long e0v = Led[i - base];
        acc = fmaf(__int_as_float((int)(e0v >> 32)),
                   h[(size_t)(unsigned)(e0v & 0xffffffffLL) * DD + col], acc);
      }
    }
    acc += __shfl_xor(acc, 32, 64);
    if (sub == 0) hnv[(size_t)(first + w) * DD + col] = acc;
  }
}

// ---------------------------------------------------------------- MFMA dual-GEMM + fused l2norm
// hOut[r,:] = l2norm( relu( sum_k A'[r,k]*B'[k,c] + lb[c] ) ), A' = [h | hnv] (K=512).
// Tile: 32 rows x 256 cols (full width) per block; 4 waves of 32x64; grid = 627 (exact).
#define TRU 32
#define KC 32
__global__ __launch_bounds__(256) void kUpdM(const float* __restrict__ A,
                                             const float* __restrict__ Av,
                                             const short* __restrict__ Bth,
                                             const short* __restrict__ Btl,
                                             const float* __restrict__ lb,
                                             float* __restrict__ out) {
  __shared__ __align__(16) short Ah[TRU][KC];
  __shared__ __align__(16) short Al[TRU][KC];
  __shared__ __align__(16) short Bh[DD][KC];
  __shared__ __align__(16) short Bl[DD][KC];
  __shared__ float ssq[4][TRU];
  const int t = threadIdx.x;
  const int rb = blockIdx.x * TRU;
  const int wid = t >> 6;
  const int lane = t & 63;
  const int wc = wid * 64;         // wave col offset (4 waves cover 256 cols)
  const int m16 = lane & 15;
  const int kg = lane >> 4;        // 0..3

  floatx4 acc[2][4];
  #pragma unroll
  for (int ct = 0; ct < 4; ct++) {
    float b = lb[wc + ct * 16 + m16];
    #pragma unroll
    for (int rt = 0; rt < 2; rt++) acc[rt][ct] = (floatx4){b, b, b, b};
  }

  for (int kc = 0; kc < 512 / KC; ++kc) {
    const int k0 = kc * KC;
    const float* src = (k0 < DD) ? (A + k0) : (Av + (k0 - DD));
    // ---- stage A (fp32 -> hi/lo bf16), 32 rows x 32 k = 256 float4 (1/thread)
    {
      int r = t >> 3;              // 0..31
      int q = t & 7;               // float4 index within row
      float4 v = *(const float4*)(src + (size_t)(rb + r) * DD + q * 4);
      short s0 = f2bf(v.x), s1 = f2bf(v.y), s2 = f2bf(v.z), s3 = f2bf(v.w);
      short l0 = f2bf(v.x - bf2f(s0)), l1 = f2bf(v.y - bf2f(s1));
      short l2 = f2bf(v.z - bf2f(s2)), l3 = f2bf(v.w - bf2f(s3));
      uint2 whi, wlo;
      whi.x = (unsigned short)s0 | ((unsigned)(unsigned short)s1 << 16);
      whi.y = (unsigned short)s2 | ((unsigned)(unsigned short)s3 << 16);
      wlo.x = (unsigned short)l0 | ((unsigned)(unsigned short)l1 << 16);
      wlo.y = (unsigned short)l2 | ((unsigned)(unsigned short)l3 << 16);
      *(uint2*)&Ah[r][q * 4] = whi;
      *(uint2*)&Al[r][q * 4] = wlo;
    }
    // ---- stage B (pre-split bf16, straight copy), 256 n x 32 k per plane
    #pragma unroll
    for (int it = 0; it < 4; ++it) {
      int idx = t + it * 256;      // 0..1023
      int n = idx >> 2;            // 0..255
      int sg = idx & 3;            // 16B segment
      *(uint4*)&Bh[n][sg * 8] = *((const uint4*)(Bth + (size_t)n * 512 + k0) + sg);
      *(uint4*)&Bl[n][sg * 8] = *((const uint4*)(Btl + (size_t)n * 512 + k0) + sg);
    }
    __syncthreads();
    // ---- fragments + MFMA
    short8 af[2], al_[2], bf_[4], bl_[4];
    #pragma unroll
    for (int rt = 0; rt < 2; rt++) {
      af[rt]  = *(const short8*)&Ah[rt * 16 + m16][kg * 8];
      al_[rt] = *(const short8*)&Al[rt * 16 + m16][kg * 8];
    }
    #pragma unroll
    for (int ct = 0; ct < 4; ct++) {
      bf_[ct] = *(const short8*)&Bh[wc + ct * 16 + m16][kg * 8];
      bl_[ct] = *(const short8*)&Bl[wc + ct * 16 + m16][kg * 8];
    }
    #pragma unroll
    for (int rt = 0; rt < 2; rt++)
      #pragma unroll
      for (int ct = 0; ct < 4; ct++) {
        acc[rt][ct] = __builtin_amdgcn_mfma_f32_16x16x32_bf16(af[rt], bf_[ct], acc[rt][ct], 0, 0, 0);
        acc[rt][ct] = __builtin_amdgcn_mfma_f32_16x16x32_bf16(af[rt], bl_[ct], acc[rt][ct], 0, 0, 0);
        acc[rt][ct] = __builtin_amdgcn_mfma_f32_16x16x32_bf16(al_[rt], bf_[ct], acc[rt][ct], 0, 0, 0);
      }
    __syncthreads();
  }
  // ---- epilogue: relu + row l2norm + store (C/D: col=lane&15, row=(lane>>4)*4+reg)
  float p[2][4];
  #pragma unroll
  for (int rt = 0; rt < 2; rt++)
    #pragma unroll
    for (int reg = 0; reg < 4; reg++) {
      float s = 0.f;
      #pragma unroll
      for (int ct = 0; ct < 4; ct++) {
        float x = fmaxf(acc[rt][ct][reg], 0.f);
        s = fmaf(x, x, s);
      }
      p[rt][reg] = s;
    }
  #pragma unroll
  for (int o = 1; o < 16; o <<= 1)
    #pragma unroll
    for (int rt = 0; rt < 2; rt++)
      #pragma unroll
      for (int reg = 0; reg < 4; reg++)
        p[rt][reg] += __shfl_xor(p[rt][reg], o, 64);
  if (m16 == 0) {
    #pragma unroll
    for (int rt = 0; rt < 2; rt++)
      #pragma unroll
      for (int reg = 0; reg < 4; reg++)
        ssq[wid][rt * 16 + kg * 4 + reg] = p[rt][reg];
  }
  __syncthreads();
  #pragma unroll
  for (int rt = 0; rt < 2; rt++) {
    #pragma unroll
    for (int reg = 0; reg < 4; reg++) {
      int row = rt * 16 + kg * 4 + reg;
      float ss = ssq[0][row] + ssq[1][row] + ssq[2][row] + ssq[3][row];
      float inv = 1.f / fmaxf(sqrtf(ss), 1e-12f);
      #pragma unroll
      for (int ct = 0; ct < 4; ct++) {
        int col = wc + ct * 16 + m16;
        out[(size_t)(rb + row) * DD + col] = fmaxf(acc[rt][ct][reg], 0.f) * inv;
      }
    }
  }
}

// ---------------------------------------------------------------- decode
__global__ __launch_bounds__(256) void kDec(const float* __restrict__ h,
                                            const int* __restrict__ aidx,
                                            const float* __restrict__ W4,
                                            const float* __restrict__ W5,
                                            float* __restrict__ Q) {
  __shared__ float tmp[4];
  int b = blockIdx.x, j = threadIdx.x;
  float s = blockSum256(h[(size_t)(NN + b) * DD + j] * W4[j], tmp);
  int a = aidx[b];
  float za = h[(size_t)a * DD + j];
  float q = blockSum256(fmaxf(za * s, 0.f) * W5[j], tmp);
  if (j == 0) Q[b] = q;
}

// ---------------------------------------------------------------- launcher
extern "C" void kernel_launch(void* const* d_in, const int* in_sizes, int n_in,
                              void* d_out, int out_size, void* d_ws, size_t ws_size,
                              hipStream_t stream) {
  (void)in_sizes; (void)n_in; (void)out_size; (void)ws_size;
  const int*   edge_src = (const int*)d_in[0];
  const int*   edge_dst = (const int*)d_in[1];
  const float* edge_w   = (const float*)d_in[2];
  const int*   bassign  = (const int*)d_in[3];
  const int*   aidx     = (const int*)d_in[4];
  const float* Xf       = (const float*)d_in[5];
  const float* Xs       = (const float*)d_in[6];
  const float* W1       = (const float*)d_in[7];
  const float* W2       = (const float*)d_in[8];
  const float* W3       = (const float*)d_in[9];
  const float* linW     = (const float*)d_in[10];
  const float* linB     = (const float*)d_in[11];
  const float* W4       = (const float*)d_in[12];
  const float* W5       = (const float*)d_in[13];
  float* Q = (float*)d_out;

  char* base = (char*)d_ws;
  const size_t NB = (size_t)NT * DD * 4;   // rows include hs
  float* hA   = (float*)(base);
  float* hnv  = (float*)(base + NB);
  float* hB   = (float*)(base + 2 * NB);
  size_t o = 3 * NB;
  short* Bth  = (short*)(base + o); o += (size_t)DD * 512 * 2;
  short* Btl  = (short*)(base + o); o += (size_t)DD * 512 * 2;
  long long* sedge = (long long*)(base + o); o += (size_t)EE * 8;
  int*   snode= (int*)(base + o);   o += (size_t)NN * 4;
  int*   cntn = (int*)(base + o);   o += (size_t)NN * 4;
  int*   cntb = (int*)(base + o);   o += (size_t)BB * 4;   // contiguous with cntn
  int*   offn = (int*)(base + o);   o += (size_t)(NN + 4) * 4;
  int*   offb = (int*)(base + o);   o += (size_t)(BB + 4) * 4;
  int*   curn = (int*)(base + o);   o += (size_t)NN * 4;
  int*   curb = (int*)(base + o);   o += (size_t)BB * 4;

  hipMemsetAsync(cntn, 0, (size_t)(NN + BB) * 4, stream);

  kM<<<512, 256, 0, stream>>>(W2, W3, linW, Bth, Btl);
  kEncCount<<<NCB + NT / 4, 256, 0, stream>>>(Xf, Xs, W1, hA,
                                              edge_dst, bassign, cntn, cntb);
  kScan<<<1, 1024, 0, stream>>>(cntn, offn, curn, cntb, offb, curb);
  kScatter<<<(EE + 255) / 256, 256, 0, stream>>>(edge_src, edge_dst, edge_w, bassign,
                                                 curn, curb, sedge, snode);
  float* hc = hA;
  float* hn = hB;
  for (int d = 0; d < DEPTH; d++) {
    kAgg<<<8 * (NT / 4), 256, 0, stream>>>(hc, offn, sedge, offb, snode, hnv);
    kUpdM<<<NT / TRU, 256, 0, stream>>>(hc, hnv, Bth, Btl, linB, hn);
    float* sw2 = hc; hc = hn; hn = sw2;
  }
  kDec<<<BB, 256, 0, stream>>>(hc, aidx, W4, W5, Q);
}

// Round 9
// 455.716 us; speedup vs baseline: 1.2898x; 1.0195x over previous
//
#include <hip/hip_runtime.h>

#define NN 20000
#define EE 320000
#define BB 64
#define DD 256
#define DEPTH 3
#define NT (NN + BB)   // h rows + hs rows appended (NT = 20064 = 32*627 = 4*5016)

typedef __attribute__((ext_vector_type(8))) short short8;
typedef __attribute__((ext_vector_type(4))) float floatx4;

// ---------------------------------------------------------------- bf16 split helpers
__device__ __forceinline__ short f2bf(float x) {
  union { float f; unsigned u; } v; v.f = x;
  unsigned r = v.u + 0x7fffu + ((v.u >> 16) & 1u);  // RNE
  return (short)(r >> 16);
}
__device__ __forceinline__ float bf2f(short s) {
  union { unsigned u; float f; } v; v.u = ((unsigned)(unsigned short)s) << 16;
  return v.f;
}

// ---------------------------------------------------------------- reductions
__device__ __forceinline__ float blockSum256(float v, float* tmp) {
  #pragma unroll
  for (int o = 32; o > 0; o >>= 1) v += __shfl_down(v, o, 64);
  if ((threadIdx.x & 63) == 0) tmp[threadIdx.x >> 6] = v;
  __syncthreads();
  float r = tmp[0] + tmp[1] + tmp[2] + tmp[3];
  __syncthreads();
  return r;
}

// ---------------------------------------------------------------- M2/M3 -> split transposed B
__global__ __launch_bounds__(256) void kM(const float* __restrict__ W2,
                                          const float* __restrict__ W3,
                                          const float* __restrict__ linW,
                                          short* __restrict__ Bth,
                                          short* __restrict__ Btl) {
  int i = blockIdx.x & 255;
  bool second = blockIdx.x >= 256;
  const float* W = second ? W3 : W2;
  const float* L = linW + (second ? DD * DD : 0);
  int j = threadIdx.x;
  float acc = 0.f;
  #pragma unroll 4
  for (int k = 0; k < DD; k++) acc = fmaf(W[i * DD + k], L[k * DD + j], acc);
  short hi = f2bf(acc);
  short lo = f2bf(acc - bf2f(hi));
  int kk = second ? (DD + i) : i;
  Bth[(size_t)j * 512 + kk] = hi;
  Btl[(size_t)j * 512 + kk] = lo;
}

// ---------------------------------------------------------------- count (first) + encode (wave-per-row)
#define NCB ((EE + 255) / 256)   // 1250 count blocks, scheduled first
__global__ __launch_bounds__(256) void kEncCount(const float* __restrict__ X,
                                                 const float* __restrict__ Xs,
                                                 const float* __restrict__ W1,
                                                 float* __restrict__ h,
                                                 const int* __restrict__ dst,
                                                 const int* __restrict__ bassign,
                                                 int* cntn, int* cntb) {
  int bid = blockIdx.x, j = threadIdx.x;
  if (bid < NCB) {
    int t = bid * 256 + j;
    if (t < EE) atomicAdd(&cntn[dst[t]], 1);
    if (t < NN) atomicAdd(&cntb[bassign[t]], 1);
  } else {
    int r = (bid - NCB) * 4 + (j >> 6);     // wave-per-row
    int lane = j & 63, c0 = lane * 4;
    const float* x = (r < NN) ? (X + (size_t)r * 2) : (Xs + (size_t)(r - NN) * 2);
    float x0 = x[0], x1 = x[1];
    float4 wa = *(const float4*)(W1 + c0);
    float4 wb = *(const float4*)(W1 + DD + c0);
    float4 v;
    v.x = fmaxf(fmaf(x0, wa.x, x1 * wb.x), 0.f);
    v.y = fmaxf(fmaf(x0, wa.y, x1 * wb.y), 0.f);
    v.z = fmaxf(fmaf(x0, wa.z, x1 * wb.z), 0.f);
    v.w = fmaxf(fmaf(x0, wa.w, x1 * wb.w), 0.f);
    float ss = v.x * v.x + v.y * v.y + v.z * v.z + v.w * v.w;
    #pragma unroll
    for (int o = 1; o < 64; o <<= 1) ss += __shfl_xor(ss, o, 64);
    float inv = 1.f / fmaxf(sqrtf(ss), 1e-12f);
    v.x *= inv; v.y *= inv; v.z *= inv; v.w *= inv;
    *(float4*)(h + (size_t)r * DD + c0) = v;
  }
}

// ---------------------------------------------------------------- CSR scan
__global__ __launch_bounds__(1024) void kScan(const int* __restrict__ cntn,
                                              int* offn, int* curn,
                                              const int* __restrict__ cntb,
                                              int* offb, int* curb) {
  __shared__ int sums[1024];
  int t = threadIdx.x;
  const int CH = 20;  // 1024*20 = 20480 >= NN
  int base = t * CH;
  int local[CH];
  int s = 0;
  #pragma unroll
  for (int i = 0; i < CH; i++) {
    int idx = base + i;
    int v = (idx < NN) ? cntn[idx] : 0;
    local[i] = s;
    s += v;
  }
  sums[t] = s;
  __syncthreads();
  for (int o = 1; o < 1024; o <<= 1) {
    int x = (t >= o) ? sums[t - o] : 0;
    __syncthreads();
    sums[t] += x;
    __syncthreads();
  }
  int excl = sums[t] - s;
  #pragma unroll
  for (int i = 0; i < CH; i++) {
    int idx = base + i;
    if (idx < NN) {
      int o = excl + local[i];
      offn[idx] = o;
      curn[idx] = o;
    }
  }
  if (t == 1023) offn[NN] = sums[1023];
  // batch offsets: 64-lane shuffle scan (first wave)
  if (t < 64) {
    int v = cntb[t];
    int incl = v;
    #pragma unroll
    for (int o = 1; o < 64; o <<= 1) {
      int x = __shfl_up(incl, o, 64);
      if (t >= o) incl += x;
    }
    int excl2 = incl - v;
    offb[t] = excl2;
    curb[t] = excl2;
    if (t == 63) offb[BB] = incl;
  }
}

__global__ __launch_bounds__(256) void kScatter(const int* __restrict__ src,
                                                const int* __restrict__ dst,
                                                const float* __restrict__ w,
                                                const int* __restrict__ bassign,
                                                int* curn, int* curb,
                                                long long* sedge, int* snode) {
  int t = blockIdx.x * 256 + threadIdx.x;
  if (t < EE) {
    int d = dst[t];
    int p = atomicAdd(&curn[d], 1);
    unsigned long long e = (unsigned long long)(unsigned)src[t]
                         | ((unsigned long long)(unsigned)__float_as_int(w[t]) << 32);
    sedge[p] = (long long)e;
  }
  if (t < NN) {
    int b = bassign[t];
    int p = atomicAdd(&curb[b], 1);
    snode[p] = t;
  }
}

// ---------------------------------------------------------------- aggregation (XCD-sliced, float4 gathers)
// 8 feature slices of 32 cols; slice = blockIdx&7 -> per-XCD h hot set = 2.56MB (L2-resident).
// Block = 4 waves = 4 consecutive nodes of one slice. Lane = edgeGroup*8 + piece:
// one global_load_dwordx4 serves 8 edges x 32 cols (8 cache lines) -> 4x fewer gather
// instrs than 4B/lane layout (round-8 was issue-bound: VALUBusy 47%, HBM 10%).
// Edge lists staged in LDS; invalid lanes get weight 0 (branchless tail).
#define ECAP 1024   // staged edges per chunk (8 KB)
__global__ __launch_bounds__(256) void kAgg(const float* __restrict__ h,
                                            const int* __restrict__ offn,
                                            const long long* __restrict__ sedge,
                                            const int* __restrict__ offb,
                                            const int* __restrict__ snode,
                                            float* __restrict__ hnv) {
  __shared__ __align__(16) long long Led[ECAP];
  int bid = blockIdx.x;
  int slice = bid & 7, group = bid >> 3;      // group 0..5015
  int t = threadIdx.x;
  int w = t >> 6, lane = t & 63;
  int eg = lane >> 3;          // edge group 0..7
  int pc = lane & 7;           // float4 piece 0..7
  int colB = slice * 32 + pc * 4;
  float4 acc = make_float4(0.f, 0.f, 0.f, 0.f);

  if (group < 16) {
    // ---- batch rows: nodes 0..63, snode index list (weight 1)
    int b0 = group * 4;
    int s0 = offb[b0], e0 = offb[b0 + 4];
    int sW = offb[b0 + w], eW = offb[b0 + w + 1];
    int* Li = (int*)Led;
    for (int base = s0; base < e0; base += 2 * ECAP) {
      int cnt = min(e0 - base, 2 * ECAP);
      __syncthreads();
      for (int i = t; i < cnt; i += 256) Li[i] = snode[base + i];
      __syncthreads();
      int lo = max(sW, base), hi = min(eW, base + cnt);
      for (int i = lo; i < hi; i += 8) {
        int idx = i + eg;
        int nrow = Li[min(idx, hi - 1) - base];
        float wgt = (idx < hi) ? 1.f : 0.f;
        float4 v = *(const float4*)(h + (size_t)nrow * DD + colB);
        acc.x = fmaf(wgt, v.x, acc.x);
        acc.y = fmaf(wgt, v.y, acc.y);
        acc.z = fmaf(wgt, v.z, acc.z);
        acc.w = fmaf(wgt, v.w, acc.w);
      }
    }
    #pragma unroll
    for (int o = 8; o < 64; o <<= 1) {
      acc.x += __shfl_xor(acc.x, o, 64);
      acc.y += __shfl_xor(acc.y, o, 64);
      acc.z += __shfl_xor(acc.z, o, 64);
      acc.w += __shfl_xor(acc.w, o, 64);
    }
    if (eg == 0) *(float4*)(hnv + (size_t)(NN + b0 + w) * DD + colB) = acc;
  } else {
    // ---- edge nodes
    int first = group * 4 - BB;                // node range [first, first+4)
    int s0 = offn[first], e0 = offn[first + 4];
    int sW = offn[first + w], eW = offn[first + w + 1];
    for (int base = s0; base < e0; base += ECAP) {
      int cnt = min(e0 - base, ECAP);
      __syncthreads();
      for (int i = t; i < cnt; i += 256) Led[i] = sedge[base + i];
      __syncthreads();
      int lo = max(sW, base), hi = min(eW, base + cnt);
      for (int i = lo; i < hi; i += 8) {
        int idx = i + eg;
        long long ev = Led[min(idx, hi - 1) - base];
        float wgt = (idx < hi) ? __int_as_float((int)(ev >> 32)) : 0.f;
        unsigned srow = (unsigned)(ev & 0xffffffffLL);
        float4 v = *(const float4*)(h + (size_t)srow * DD + colB);
        acc.x = fmaf(wgt, v.x, acc.x);
        acc.y = fmaf(wgt, v.y, acc.y);
        acc.z = fmaf(wgt, v.z, acc.z);
        acc.w = fmaf(wgt, v.w, acc.w);
      }
    }
    #pragma unroll
    for (int o = 8; o < 64; o <<= 1) {
      acc.x += __shfl_xor(acc.x, o, 64);
      acc.y += __shfl_xor(acc.y, o, 64);
      acc.z += __shfl_xor(acc.z, o, 64);
      acc.w += __shfl_xor(acc.w, o, 64);
    }
    if (eg == 0) *(float4*)(hnv + (size_t)(first + w) * DD + colB) = acc;
  }
}

// ---------------------------------------------------------------- MFMA dual-GEMM + fused l2norm
// hOut[r,:] = l2norm( relu( sum_k A'[r,k]*B'[k,c] + lb[c] ) ), A' = [h | hnv] (K=512).
// Tile: 32 rows x 256 cols (full width) per block; 4 waves of 32x64; grid = 627 (exact).
#define TRU 32
#define KC 32
__global__ __launch_bounds__(256) void kUpdM(const float* __restrict__ A,
                                             const float* __restrict__ Av,
                                             const short* __restrict__ Bth,
                                             const short* __restrict__ Btl,
                                             const float* __restrict__ lb,
                                             float* __restrict__ out) {
  __shared__ __align__(16) short Ah[TRU][KC];
  __shared__ __align__(16) short Al[TRU][KC];
  __shared__ __align__(16) short Bh[DD][KC];
  __shared__ __align__(16) short Bl[DD][KC];
  __shared__ float ssq[4][TRU];
  const int t = threadIdx.x;
  const int rb = blockIdx.x * TRU;
  const int wid = t >> 6;
  const int lane = t & 63;
  const int wc = wid * 64;         // wave col offset (4 waves cover 256 cols)
  const int m16 = lane & 15;
  const int kg = lane >> 4;        // 0..3

  floatx4 acc[2][4];
  #pragma unroll
  for (int ct = 0; ct < 4; ct++) {
    float b = lb[wc + ct * 16 + m16];
    #pragma unroll
    for (int rt = 0; rt < 2; rt++) acc[rt][ct] = (floatx4){b, b, b, b};
  }

  for (int kc = 0; kc < 512 / KC; ++kc) {
    const int k0 = kc * KC;
    const float* src = (k0 < DD) ? (A + k0) : (Av + (k0 - DD));
    // ---- stage A (fp32 -> hi/lo bf16), 32 rows x 32 k = 256 float4 (1/thread)
    {
      int r = t >> 3;              // 0..31
      int q = t & 7;               // float4 index within row
      float4 v = *(const float4*)(src + (size_t)(rb + r) * DD + q * 4);
      short s0 = f2bf(v.x), s1 = f2bf(v.y), s2 = f2bf(v.z), s3 = f2bf(v.w);
      short l0 = f2bf(v.x - bf2f(s0)), l1 = f2bf(v.y - bf2f(s1));
      short l2 = f2bf(v.z - bf2f(s2)), l3 = f2bf(v.w - bf2f(s3));
      uint2 whi, wlo;
      whi.x = (unsigned short)s0 | ((unsigned)(unsigned short)s1 << 16);
      whi.y = (unsigned short)s2 | ((unsigned)(unsigned short)s3 << 16);
      wlo.x = (unsigned short)l0 | ((unsigned)(unsigned short)l1 << 16);
      wlo.y = (unsigned short)l2 | ((unsigned)(unsigned short)l3 << 16);
      *(uint2*)&Ah[r][q * 4] = whi;
      *(uint2*)&Al[r][q * 4] = wlo;
    }
    // ---- stage B (pre-split bf16, straight copy), 256 n x 32 k per plane
    #pragma unroll
    for (int it = 0; it < 4; ++it) {
      int idx = t + it * 256;      // 0..1023
      int n = idx >> 2;            // 0..255
      int sg = idx & 3;            // 16B segment
      *(uint4*)&Bh[n][sg * 8] = *((const uint4*)(Bth + (size_t)n * 512 + k0) + sg);
      *(uint4*)&Bl[n][sg * 8] = *((const uint4*)(Btl + (size_t)n * 512 + k0) + sg);
    }
    __syncthreads();
    // ---- fragments + MFMA
    short8 af[2], al_[2], bf_[4], bl_[4];
    #pragma unroll
    for (int rt = 0; rt < 2; rt++) {
      af[rt]  = *(const short8*)&Ah[rt * 16 + m16][kg * 8];
      al_[rt] = *(const short8*)&Al[rt * 16 + m16][kg * 8];
    }
    #pragma unroll
    for (int ct = 0; ct < 4; ct++) {
      bf_[ct] = *(const short8*)&Bh[wc + ct * 16 + m16][kg * 8];
      bl_[ct] = *(const short8*)&Bl[wc + ct * 16 + m16][kg * 8];
    }
    #pragma unroll
    for (int rt = 0; rt < 2; rt++)
      #pragma unroll
      for (int ct = 0; ct < 4; ct++) {
        acc[rt][ct] = __builtin_amdgcn_mfma_f32_16x16x32_bf16(af[rt], bf_[ct], acc[rt][ct], 0, 0, 0);
        acc[rt][ct] = __builtin_amdgcn_mfma_f32_16x16x32_bf16(af[rt], bl_[ct], acc[rt][ct], 0, 0, 0);
        acc[rt][ct] = __builtin_amdgcn_mfma_f32_16x16x32_bf16(al_[rt], bf_[ct], acc[rt][ct], 0, 0, 0);
      }
    __syncthreads();
  }
  // ---- epilogue: relu + row l2norm + store (C/D: col=lane&15, row=(lane>>4)*4+reg)
  float p[2][4];
  #pragma unroll
  for (int rt = 0; rt < 2; rt++)
    #pragma unroll
    for (int reg = 0; reg < 4; reg++) {
      float s = 0.f;
      #pragma unroll
      for (int ct = 0; ct < 4; ct++) {
        float x = fmaxf(acc[rt][ct][reg], 0.f);
        s = fmaf(x, x, s);
      }
      p[rt][reg] = s;
    }
  #pragma unroll
  for (int o = 1; o < 16; o <<= 1)
    #pragma unroll
    for (int rt = 0; rt < 2; rt++)
      #pragma unroll
      for (int reg = 0; reg < 4; reg++)
        p[rt][reg] += __shfl_xor(p[rt][reg], o, 64);
  if (m16 == 0) {
    #pragma unroll
    for (int rt = 0; rt < 2; rt++)
      #pragma unroll
      for (int reg = 0; reg < 4; reg++)
        ssq[wid][rt * 16 + kg * 4 + reg] = p[rt][reg];
  }
  __syncthreads();
  #pragma unroll
  for (int rt = 0; rt < 2; rt++) {
    #pragma unroll
    for (int reg = 0; reg < 4; reg++) {
      int row = rt * 16 + kg * 4 + reg;
      float ss = ssq[0][row] + ssq[1][row] + ssq[2][row] + ssq[3][row];
      float inv = 1.f / fmaxf(sqrtf(ss), 1e-12f);
      #pragma unroll
      for (int ct = 0; ct < 4; ct++) {
        int col = wc + ct * 16 + m16;
        out[(size_t)(rb + row) * DD + col] = fmaxf(acc[rt][ct][reg], 0.f) * inv;
      }
    }
  }
}

// ---------------------------------------------------------------- decode
__global__ __launch_bounds__(256) void kDec(const float* __restrict__ h,
                                            const int* __restrict__ aidx,
                                            const float* __restrict__ W4,
                                            const float* __restrict__ W5,
                                            float* __restrict__ Q) {
  __shared__ float tmp[4];
  int b = blockIdx.x, j = threadIdx.x;
  float s = blockSum256(h[(size_t)(NN + b) * DD + j] * W4[j], tmp);
  int a = aidx[b];
  float za = h[(size_t)a * DD + j];
  float q = blockSum256(fmaxf(za * s, 0.f) * W5[j], tmp);
  if (j == 0) Q[b] = q;
}

// ---------------------------------------------------------------- launcher
extern "C" void kernel_launch(void* const* d_in, const int* in_sizes, int n_in,
                              void* d_out, int out_size, void* d_ws, size_t ws_size,
                              hipStream_t stream) {
  (void)in_sizes; (void)n_in; (void)out_size; (void)ws_size;
  const int*   edge_src = (const int*)d_in[0];
  const int*   edge_dst = (const int*)d_in[1];
  const float* edge_w   = (const float*)d_in[2];
  const int*   bassign  = (const int*)d_in[3];
  const int*   aidx     = (const int*)d_in[4];
  const float* Xf       = (const float*)d_in[5];
  const float* Xs       = (const float*)d_in[6];
  const float* W1       = (const float*)d_in[7];
  const float* W2       = (const float*)d_in[8];
  const float* W3       = (const float*)d_in[9];
  const float* linW     = (const float*)d_in[10];
  const float* linB     = (const float*)d_in[11];
  const float* W4       = (const float*)d_in[12];
  const float* W5       = (const float*)d_in[13];
  float* Q = (float*)d_out;

  char* base = (char*)d_ws;
  const size_t NB = (size_t)NT * DD * 4;   // rows include hs
  float* hA   = (float*)(base);
  float* hnv  = (float*)(base + NB);
  float* hB   = (float*)(base + 2 * NB);
  size_t o = 3 * NB;
  short* Bth  = (short*)(base + o); o += (size_t)DD * 512 * 2;
  short* Btl  = (short*)(base + o); o += (size_t)DD * 512 * 2;
  long long* sedge = (long long*)(base + o); o += (size_t)EE * 8;
  int*   snode= (int*)(base + o);   o += (size_t)NN * 4;
  int*   cntn = (int*)(base + o);   o += (size_t)NN * 4;
  int*   cntb = (int*)(base + o);   o += (size_t)BB * 4;   // contiguous with cntn
  int*   offn = (int*)(base + o);   o += (size_t)(NN + 4) * 4;
  int*   offb = (int*)(base + o);   o += (size_t)(BB + 4) * 4;
  int*   curn = (int*)(base + o);   o += (size_t)NN * 4;
  int*   curb = (int*)(base + o);   o += (size_t)BB * 4;

  hipMemsetAsync(cntn, 0, (size_t)(NN + BB) * 4, stream);

  kM<<<512, 256, 0, stream>>>(W2, W3, linW, Bth, Btl);
  kEncCount<<<NCB + NT / 4, 256, 0, stream>>>(Xf, Xs, W1, hA,
                                              edge_dst, bassign, cntn, cntb);
  kScan<<<1, 1024, 0, stream>>>(cntn, offn, curn, cntb, offb, curb);
  kScatter<<<(EE + 255) / 256, 256, 0, stream>>>(edge_src, edge_dst, edge_w, bassign,
                                                 curn, curb, sedge, snode);
  float* hc = hA;
  float* hn = hB;
  for (int d = 0; d < DEPTH; d++) {
    kAgg<<<8 * (NT / 4), 256, 0, stream>>>(hc, offn, sedge, offb, snode, hnv);
    kUpdM<<<NT / TRU, 256, 0, stream>>>(hc, hnv, Bth, Btl, linB, hn);
    float* sw2 = hc; hc = hn; hn = sw2;
  }
  kDec<<<BB, 256, 0, stream>>>(hc, aidx, W4, W5, Q);
}